// Round 4
// baseline (484.220 us; speedup 1.0000x reference)
//
#include <hip/hip_runtime.h>
#include <hip/hip_bf16.h>

// Problem constants (from setup_inputs): B=4, S=2048, D_IN=2048, D_OUT=2048
constexpr int D_IN  = 2048;
constexpr int D_OUT = 2048;
constexpr int GM = 4 * 2048;      // B*S rows
constexpr int GK = 2 * D_IN;      // 4096 (concat real|imag)
constexpr int GN = 2 * D_OUT;     // 4096 (concat y_real|y_imag channels)

typedef __attribute__((ext_vector_type(8))) short bf16x8;
typedef __attribute__((ext_vector_type(4))) float f32x4;

constexpr int QB = 1024;          // quant kernel blocks

// Exact bf16 bit patterns for {0, +-0.5, +-1}; negate = XOR 0x8000.
__device__ inline unsigned short q4bits(float w) {
    if (w >  0.75f) return 0x3F80;   // 1.0
    if (w >  0.25f) return 0x3F00;   // 0.5
    if (w < -0.75f) return 0xBF80;   // -1.0
    if (w < -0.25f) return 0xBF00;   // -0.5
    return 0;
}

__device__ inline unsigned short bf16b(float x) {
    __hip_bfloat16 h = __float2bfloat16(x);
    unsigned short u;
    __builtin_memcpy(&u, &h, 2);
    return u;
}

// ---------------------------------------------------------------------------
// Kernel 1: quantize weights into W_cat (bf16, GN x GK, row-major); per-block
// partial sums of |w_re|, |w_im|. Fully coalesced float4 loads / ushort4 stores.
// W_cat row n<2048:  [ qre[n,:] | -qim[n,:] ]   -> y_real channels
// W_cat row n>=2048: [ qim[n,:] |  qre[n,:] ]   -> y_imag channels
// ---------------------------------------------------------------------------
__global__ __launch_bounds__(256) void quant_kernel(
        const float* __restrict__ wre, const float* __restrict__ wim,
        unsigned short* __restrict__ wq, float* __restrict__ partial) {
    float a = 0.f, b = 0.f;
    int tid = blockIdx.x * 256 + threadIdx.x;     // 0 .. 262143
    const float4* wre4 = (const float4*)wre;
    const float4* wim4 = (const float4*)wim;
    for (int c = 0; c < 4; c++) {
        int f4i = tid + c * (QB * 256);           // float4 index, coalesced
        int idx = f4i * 4;
        int o = idx >> 11;                        // row in D_OUT
        int k = idx & (D_IN - 1);                 // col in D_IN (multiple of 4)
        float4 r = wre4[f4i];
        float4 im = wim4[f4i];
        a += fabsf(r.x) + fabsf(r.y) + fabsf(r.z) + fabsf(r.w);
        b += fabsf(im.x) + fabsf(im.y) + fabsf(im.z) + fabsf(im.w);
        ushort4 qre, qim, nim;
        qre.x = q4bits(r.x);  qre.y = q4bits(r.y);  qre.z = q4bits(r.z);  qre.w = q4bits(r.w);
        qim.x = q4bits(im.x); qim.y = q4bits(im.y); qim.z = q4bits(im.z); qim.w = q4bits(im.w);
        nim.x = qim.x ^ 0x8000; nim.y = qim.y ^ 0x8000;
        nim.z = qim.z ^ 0x8000; nim.w = qim.w ^ 0x8000;
        *(ushort4*)(wq + (size_t)o * GK + k)                  = qre;
        *(ushort4*)(wq + (size_t)o * GK + D_IN + k)           = nim;
        *(ushort4*)(wq + (size_t)(D_OUT + o) * GK + k)        = qim;
        *(ushort4*)(wq + (size_t)(D_OUT + o) * GK + D_IN + k) = qre;
    }
    for (int off = 32; off; off >>= 1) {
        a += __shfl_down(a, off, 64);
        b += __shfl_down(b, off, 64);
    }
    __shared__ float sa[4], sb[4];
    int lane = threadIdx.x & 63, wv = threadIdx.x >> 6;
    if (lane == 0) { sa[wv] = a; sb[wv] = b; }
    __syncthreads();
    if (threadIdx.x == 0) {
        partial[blockIdx.x]      = sa[0] + sa[1] + sa[2] + sa[3];
        partial[QB + blockIdx.x] = sb[0] + sb[1] + sb[2] + sb[3];
    }
}

// Tiny final reduce: partial[2*QB] -> sums[2]
__global__ __launch_bounds__(256) void reduce_kernel(
        const float* __restrict__ partial, float* __restrict__ sums) {
    int t = threadIdx.x;
    float a = 0.f, b = 0.f;
    for (int i = t; i < QB; i += 256) { a += partial[i]; b += partial[QB + i]; }
    for (int off = 32; off; off >>= 1) {
        a += __shfl_down(a, off, 64);
        b += __shfl_down(b, off, 64);
    }
    __shared__ float sa[4], sb[4];
    int lane = t & 63, wv = t >> 6;
    if (lane == 0) { sa[wv] = a; sb[wv] = b; }
    __syncthreads();
    if (t == 0) {
        sums[0] = sa[0] + sa[1] + sa[2] + sa[3];
        sums[1] = sb[0] + sb[1] + sb[2] + sb[3];
    }
}

// ---------------------------------------------------------------------------
// Kernel 2: LayerNorm over concat row [x_real[m,:], x_imag[m,:]] (4096 elems),
// writes bf16 activations A (GM x GK row-major). One 256-thread block per row.
// ---------------------------------------------------------------------------
__global__ __launch_bounds__(256) void ln_kernel(
        const float* __restrict__ xr, const float* __restrict__ xi,
        const float* __restrict__ gamma, const float* __restrict__ beta,
        unsigned short* __restrict__ A) {
    int m = blockIdx.x;
    int t = threadIdx.x;
    const float4* r4 = (const float4*)(xr + (size_t)m * D_IN);
    const float4* i4 = (const float4*)(xi + (size_t)m * D_IN);
    float4 vr[2], vi[2];
    float s = 0.f, ss = 0.f;
    for (int c = 0; c < 2; c++) {
        float4 v = r4[t + c * 256];
        vr[c] = v;
        s  += v.x + v.y + v.z + v.w;
        ss += v.x * v.x + v.y * v.y + v.z * v.z + v.w * v.w;
        v = i4[t + c * 256];
        vi[c] = v;
        s  += v.x + v.y + v.z + v.w;
        ss += v.x * v.x + v.y * v.y + v.z * v.z + v.w * v.w;
    }
    for (int off = 32; off; off >>= 1) {
        s  += __shfl_down(s, off, 64);
        ss += __shfl_down(ss, off, 64);
    }
    __shared__ float red[8];
    __shared__ float smu, srs;
    int lane = t & 63, wv = t >> 6;
    if (lane == 0) { red[wv] = s; red[4 + wv] = ss; }
    __syncthreads();
    if (t == 0) {
        float S  = red[0] + red[1] + red[2] + red[3];
        float SS = red[4] + red[5] + red[6] + red[7];
        float mu  = S * (1.0f / 4096.0f);
        float var = SS * (1.0f / 4096.0f) - mu * mu;
        smu = mu;
        srs = rsqrtf(var + 1e-6f);
    }
    __syncthreads();
    float mu = smu, rs = srs;
    const float4* g4 = (const float4*)gamma;
    const float4* b4 = (const float4*)beta;
    ushort4* Arow = (ushort4*)(A + (size_t)m * GK);
    for (int c = 0; c < 2; c++) {
        int k4 = t + c * 256;                 // float4 index in real half
        float4 g = g4[k4], b = b4[k4];
        float4 v = vr[c];
        ushort4 o;
        o.x = bf16b((v.x - mu) * rs * g.x + b.x);
        o.y = bf16b((v.y - mu) * rs * g.y + b.y);
        o.z = bf16b((v.z - mu) * rs * g.z + b.z);
        o.w = bf16b((v.w - mu) * rs * g.w + b.w);
        Arow[k4] = o;
        g = g4[512 + k4]; b = b4[512 + k4];
        v = vi[c];
        o.x = bf16b((v.x - mu) * rs * g.x + b.x);
        o.y = bf16b((v.y - mu) * rs * g.y + b.y);
        o.z = bf16b((v.z - mu) * rs * g.z + b.z);
        o.w = bf16b((v.w - mu) * rs * g.w + b.w);
        Arow[512 + k4] = o;
    }
}

// ---------------------------------------------------------------------------
// Kernel 3: GEMM  Y(GM x GN) = A(GM x GK) * W_cat^T, W_cat stored N x K.
// Block tile 256x128, BK=64; 4 waves, each computes a 128x64 wave tile via
// 8x4 accumulators of 16x16x32 bf16 MFMA. Rationale: at 64x64 wave tiles the
// LDS-read pipe (8 ds_read_b128 per 16 MFMA) was the binding resource
// (164us floor vs 132us MFMA floor); 128x64 wave tiles cut ds_read/FLOP by
// 25% (12 reads per 32 MFMA -> LDS floor ~123us < MFMA floor).
// XOR-swizzled LDS (chunk p of row rr holds logical chunk p ^ (rr&7)):
// conflict-free reads, verified SQ_LDS_BANK_CONFLICT==0 in round 3.
// Staging via global_load_lds width-16; per-thread global pointers are
// strength-reduced (advance by BK per K-iter).
// ---------------------------------------------------------------------------
__global__ __launch_bounds__(256, 2) void gemm_kernel(
        const unsigned short* __restrict__ A,
        const unsigned short* __restrict__ Wq,
        const float* __restrict__ sums,
        float* __restrict__ out) {
    constexpr int BM = 256, BN = 128, BK = 64;
    __shared__ unsigned short lsA[BM * BK];
    __shared__ unsigned short lsB[BN * BK];
    int n0 = blockIdx.x * BN;
    int m0 = blockIdx.y * BM;
    int t = threadIdx.x, lane = t & 63, wave = t >> 6;
    int wm = (wave >> 1) * 128;    // wave's m offset within tile (0 or 128)
    int wn = (wave & 1) * 64;      // wave's n offset within tile
    int quad = lane >> 4, r = lane & 15;
    int srow = lane >> 3;                     // staging: row within 8-row group
    int scol = ((lane & 7) ^ srow) * 8;       // staging: swizzled bf16 col

    // Reader swizzle: logical chunk (ks*4+quad) of row rr lives at physical
    // chunk ((ks*4+quad) ^ (rr&7)); rr&7 == r&7 for all fragment rows.
    int csw0 = ((quad ^ (r & 7)) * 8);        // element offset, ks=0

    // Strength-reduced staging pointers (advance by BK per K-iter).
    const unsigned short* gA = A  + (size_t)(m0 + wave * 8 + srow) * GK + scol;
    const unsigned short* gB = Wq + (size_t)(n0 + wave * 8 + srow) * GK + scol;

    f32x4 acc[8][4] = {};

    for (int k0 = 0; k0 < GK; k0 += BK) {
        // stage A tile (256 rows x 64 cols bf16): 8 issues of 16B per thread
#pragma unroll
        for (int i = 0; i < 8; i++) {
            int row = i * 32 + wave * 8;
            __builtin_amdgcn_global_load_lds(
                (const __attribute__((address_space(1))) void*)(const void*)(gA + (size_t)i * 32 * GK),
                (__attribute__((address_space(3))) void*)(void*)(lsA + row * BK), 16, 0, 0);
        }
        // stage W tile (128 rows x 64 cols bf16): 4 issues per thread
#pragma unroll
        for (int i = 0; i < 4; i++) {
            int row = i * 32 + wave * 8;
            __builtin_amdgcn_global_load_lds(
                (const __attribute__((address_space(1))) void*)(const void*)(gB + (size_t)i * 32 * GK),
                (__attribute__((address_space(3))) void*)(void*)(lsB + row * BK), 16, 0, 0);
        }
        gA += BK;
        gB += BK;
        __syncthreads();
#pragma unroll
        for (int ks = 0; ks < 2; ks++) {
            bf16x8 af[8], bfr[4];
            const short* pa = (const short*)lsA;
            const short* pb = (const short*)lsB;
            int coff = csw0 ^ (ks * 32);
#pragma unroll
            for (int j = 0; j < 4; j++)
                bfr[j] = *(const bf16x8*)(pb + (wn + j * 16 + r) * BK + coff);
#pragma unroll
            for (int i = 0; i < 8; i++)
                af[i] = *(const bf16x8*)(pa + (wm + i * 16 + r) * BK + coff);
#pragma unroll
            for (int i = 0; i < 8; i++)
#pragma unroll
                for (int j = 0; j < 4; j++)
                    acc[i][j] = __builtin_amdgcn_mfma_f32_16x16x32_bf16(
                        af[i], bfr[j], acc[i][j], 0, 0, 0);
        }
        __syncthreads();
    }

    // Epilogue: per-block uniform half selection (BN=128 divides D_OUT)
    float s_re = sums[0] * (1.0f / (2048.0f * 2048.0f));
    float s_im = sums[1] * (1.0f / (2048.0f * 2048.0f));
    float scale;
    float* obase;
    int ncol0;
    if (n0 < D_OUT) { scale = s_re; obase = out;                        ncol0 = n0; }
    else            { scale = s_im; obase = out + (size_t)GM * D_OUT;   ncol0 = n0 - D_OUT; }

#pragma unroll
    for (int i = 0; i < 8; i++)
#pragma unroll
        for (int j = 0; j < 4; j++) {
            int mrow = m0 + wm + i * 16 + quad * 4;   // C/D layout: row=(lane>>4)*4+reg
            int ncol = ncol0 + wn + j * 16 + r;       // col = lane&15
#pragma unroll
            for (int reg = 0; reg < 4; reg++)
                obase[(size_t)(mrow + reg) * D_OUT + ncol] = acc[i][j][reg] * scale;
        }
}

extern "C" void kernel_launch(void* const* d_in, const int* in_sizes, int n_in,
                              void* d_out, int out_size, void* d_ws, size_t ws_size,
                              hipStream_t stream) {
    const float* xr    = (const float*)d_in[0];
    const float* xi    = (const float*)d_in[1];
    const float* wre   = (const float*)d_in[2];
    const float* wim   = (const float*)d_in[3];
    const float* gamma = (const float*)d_in[4];
    const float* beta  = (const float*)d_in[5];
    float* out = (float*)d_out;

    // ws layout: A bf16 (GM*GK), W_cat bf16 (GN*GK), partials (2*QB f32), sums (2 f32)
    unsigned short* A  = (unsigned short*)d_ws;
    unsigned short* Wq = (unsigned short*)((char*)d_ws + (size_t)GM * GK * 2);
    float* partial = (float*)((char*)d_ws + (size_t)GM * GK * 2 + (size_t)GN * GK * 2);
    float* sums = partial + 2 * QB;

    quant_kernel<<<QB, 256, 0, stream>>>(wre, wim, Wq, partial);
    reduce_kernel<<<1, 256, 0, stream>>>(partial, sums);
    ln_kernel<<<GM, 256, 0, stream>>>(xr, xi, gamma, beta, A);
    gemm_kernel<<<dim3(GN / 128, GM / 256), 256, 0, stream>>>(A, Wq, sums, out);
}

// Round 5
// 483.055 us; speedup vs baseline: 1.0024x; 1.0024x over previous
//
#include <hip/hip_runtime.h>
#include <hip/hip_bf16.h>

// Problem constants (from setup_inputs): B=4, S=2048, D_IN=2048, D_OUT=2048
constexpr int D_IN  = 2048;
constexpr int D_OUT = 2048;
constexpr int GM = 4 * 2048;      // B*S rows
constexpr int GK = 2 * D_IN;      // 4096 (concat real|imag)
constexpr int GN = 2 * D_OUT;     // 4096 (concat y_real|y_imag channels)

typedef __attribute__((ext_vector_type(8))) short bf16x8;
typedef __attribute__((ext_vector_type(4))) float f32x4;

constexpr int QB = 1024;          // quant kernel blocks

// Exact bf16 bit patterns for {0, +-0.5, +-1}; negate = XOR 0x8000.
__device__ inline unsigned short q4bits(float w) {
    if (w >  0.75f) return 0x3F80;   // 1.0
    if (w >  0.25f) return 0x3F00;   // 0.5
    if (w < -0.75f) return 0xBF80;   // -1.0
    if (w < -0.25f) return 0xBF00;   // -0.5
    return 0;
}

__device__ inline unsigned short bf16b(float x) {
    __hip_bfloat16 h = __float2bfloat16(x);
    unsigned short u;
    __builtin_memcpy(&u, &h, 2);
    return u;
}

// ---------------------------------------------------------------------------
// Kernel 1: quantize weights into W_cat (bf16, GN x GK, row-major); per-block
// partial sums of |w_re|, |w_im|. Fully coalesced float4 loads / ushort4 stores.
// W_cat row n<2048:  [ qre[n,:] | -qim[n,:] ]   -> y_real channels
// W_cat row n>=2048: [ qim[n,:] |  qre[n,:] ]   -> y_imag channels
// ---------------------------------------------------------------------------
__global__ __launch_bounds__(256) void quant_kernel(
        const float* __restrict__ wre, const float* __restrict__ wim,
        unsigned short* __restrict__ wq, float* __restrict__ partial) {
    float a = 0.f, b = 0.f;
    int tid = blockIdx.x * 256 + threadIdx.x;     // 0 .. 262143
    const float4* wre4 = (const float4*)wre;
    const float4* wim4 = (const float4*)wim;
    for (int c = 0; c < 4; c++) {
        int f4i = tid + c * (QB * 256);           // float4 index, coalesced
        int idx = f4i * 4;
        int o = idx >> 11;                        // row in D_OUT
        int k = idx & (D_IN - 1);                 // col in D_IN (multiple of 4)
        float4 r = wre4[f4i];
        float4 im = wim4[f4i];
        a += fabsf(r.x) + fabsf(r.y) + fabsf(r.z) + fabsf(r.w);
        b += fabsf(im.x) + fabsf(im.y) + fabsf(im.z) + fabsf(im.w);
        ushort4 qre, qim, nim;
        qre.x = q4bits(r.x);  qre.y = q4bits(r.y);  qre.z = q4bits(r.z);  qre.w = q4bits(r.w);
        qim.x = q4bits(im.x); qim.y = q4bits(im.y); qim.z = q4bits(im.z); qim.w = q4bits(im.w);
        nim.x = qim.x ^ 0x8000; nim.y = qim.y ^ 0x8000;
        nim.z = qim.z ^ 0x8000; nim.w = qim.w ^ 0x8000;
        *(ushort4*)(wq + (size_t)o * GK + k)                  = qre;
        *(ushort4*)(wq + (size_t)o * GK + D_IN + k)           = nim;
        *(ushort4*)(wq + (size_t)(D_OUT + o) * GK + k)        = qim;
        *(ushort4*)(wq + (size_t)(D_OUT + o) * GK + D_IN + k) = qre;
    }
    for (int off = 32; off; off >>= 1) {
        a += __shfl_down(a, off, 64);
        b += __shfl_down(b, off, 64);
    }
    __shared__ float sa[4], sb[4];
    int lane = threadIdx.x & 63, wv = threadIdx.x >> 6;
    if (lane == 0) { sa[wv] = a; sb[wv] = b; }
    __syncthreads();
    if (threadIdx.x == 0) {
        partial[blockIdx.x]      = sa[0] + sa[1] + sa[2] + sa[3];
        partial[QB + blockIdx.x] = sb[0] + sb[1] + sb[2] + sb[3];
    }
}

// Tiny final reduce: partial[2*QB] -> sums[2]
__global__ __launch_bounds__(256) void reduce_kernel(
        const float* __restrict__ partial, float* __restrict__ sums) {
    int t = threadIdx.x;
    float a = 0.f, b = 0.f;
    for (int i = t; i < QB; i += 256) { a += partial[i]; b += partial[QB + i]; }
    for (int off = 32; off; off >>= 1) {
        a += __shfl_down(a, off, 64);
        b += __shfl_down(b, off, 64);
    }
    __shared__ float sa[4], sb[4];
    int lane = t & 63, wv = t >> 6;
    if (lane == 0) { sa[wv] = a; sb[wv] = b; }
    __syncthreads();
    if (t == 0) {
        sums[0] = sa[0] + sa[1] + sa[2] + sa[3];
        sums[1] = sb[0] + sb[1] + sb[2] + sb[3];
    }
}

// ---------------------------------------------------------------------------
// Kernel 2: LayerNorm over concat row [x_real[m,:], x_imag[m,:]] (4096 elems),
// writes bf16 activations A (GM x GK row-major). One 256-thread block per row.
// ---------------------------------------------------------------------------
__global__ __launch_bounds__(256) void ln_kernel(
        const float* __restrict__ xr, const float* __restrict__ xi,
        const float* __restrict__ gamma, const float* __restrict__ beta,
        unsigned short* __restrict__ A) {
    int m = blockIdx.x;
    int t = threadIdx.x;
    const float4* r4 = (const float4*)(xr + (size_t)m * D_IN);
    const float4* i4 = (const float4*)(xi + (size_t)m * D_IN);
    float4 vr[2], vi[2];
    float s = 0.f, ss = 0.f;
    for (int c = 0; c < 2; c++) {
        float4 v = r4[t + c * 256];
        vr[c] = v;
        s  += v.x + v.y + v.z + v.w;
        ss += v.x * v.x + v.y * v.y + v.z * v.z + v.w * v.w;
        v = i4[t + c * 256];
        vi[c] = v;
        s  += v.x + v.y + v.z + v.w;
        ss += v.x * v.x + v.y * v.y + v.z * v.z + v.w * v.w;
    }
    for (int off = 32; off; off >>= 1) {
        s  += __shfl_down(s, off, 64);
        ss += __shfl_down(ss, off, 64);
    }
    __shared__ float red[8];
    __shared__ float smu, srs;
    int lane = t & 63, wv = t >> 6;
    if (lane == 0) { red[wv] = s; red[4 + wv] = ss; }
    __syncthreads();
    if (t == 0) {
        float S  = red[0] + red[1] + red[2] + red[3];
        float SS = red[4] + red[5] + red[6] + red[7];
        float mu  = S * (1.0f / 4096.0f);
        float var = SS * (1.0f / 4096.0f) - mu * mu;
        smu = mu;
        srs = rsqrtf(var + 1e-6f);
    }
    __syncthreads();
    float mu = smu, rs = srs;
    const float4* g4 = (const float4*)gamma;
    const float4* b4 = (const float4*)beta;
    ushort4* Arow = (ushort4*)(A + (size_t)m * GK);
    for (int c = 0; c < 2; c++) {
        int k4 = t + c * 256;                 // float4 index in real half
        float4 g = g4[k4], b = b4[k4];
        float4 v = vr[c];
        ushort4 o;
        o.x = bf16b((v.x - mu) * rs * g.x + b.x);
        o.y = bf16b((v.y - mu) * rs * g.y + b.y);
        o.z = bf16b((v.z - mu) * rs * g.z + b.z);
        o.w = bf16b((v.w - mu) * rs * g.w + b.w);
        Arow[k4] = o;
        g = g4[512 + k4]; b = b4[512 + k4];
        v = vi[c];
        o.x = bf16b((v.x - mu) * rs * g.x + b.x);
        o.y = bf16b((v.y - mu) * rs * g.y + b.y);
        o.z = bf16b((v.z - mu) * rs * g.z + b.z);
        o.w = bf16b((v.w - mu) * rs * g.w + b.w);
        Arow[512 + k4] = o;
    }
}

// ---------------------------------------------------------------------------
// Kernel 3: GEMM  Y(GM x GN) = A(GM x GK) * W_cat^T, W_cat stored N x K.
// Round-3 proven structure: 128x128 block tile, BK=64, 4 waves with 64x64
// wave tiles (4x4 acc of 16x16x32 bf16 MFMA), XOR-swizzled LDS (0 bank
// conflicts), global_load_lds width-16 staging.
// Round-5 additions:
//  - XCD-aware 1D block swizzle: xcd = blockIdx%8 owns 4 fixed N-tiles, so
//    each XCD's B working set (4 x 1MB) fits its private 4MB L2; A (64MB)
//    stays L3-resident. Cuts HBM-latency barrier drains.
//  - __launch_bounds__(256,4): round 3 used 64 VGPR + 64 AGPR = 128 regs,
//    so 4 waves/SIMD is attainable; request it for deeper barrier overlap.
//  (256x128 tile tried in round 4: reads/MFMA -25% but 2 waves/SIMD ->
//   occupancy 23% -> net regression. Do not revisit.)
// ---------------------------------------------------------------------------
__global__ __launch_bounds__(256, 4) void gemm_kernel(
        const unsigned short* __restrict__ A,
        const unsigned short* __restrict__ Wq,
        const float* __restrict__ sums,
        float* __restrict__ out) {
    constexpr int BM = 128, BN = 128, BK = 64;
    __shared__ unsigned short lsA[BM * BK];
    __shared__ unsigned short lsB[BN * BK];

    // XCD-aware swizzle: 2048 blocks, 8 XCDs round-robin by blockIdx%8.
    // XCD x owns n_tiles x*4 .. x*4+3; m_tile sweeps 0..63 per XCD.
    int lid = blockIdx.x;
    int xcd = lid & 7;
    int j = lid >> 3;                  // 0..255 within XCD
    int n_tile = xcd * 4 + (j & 3);    // 0..31
    int m_tile = j >> 2;               // 0..63
    int n0 = n_tile * BN;
    int m0 = m_tile * BM;

    int t = threadIdx.x, lane = t & 63, wave = t >> 6;
    int wm = (wave >> 1) * 64;     // wave's m offset within tile
    int wn = (wave & 1) * 64;      // wave's n offset within tile
    int quad = lane >> 4, r = lane & 15;
    int srow = lane >> 3;                     // staging: row within 8-row group
    int scol = ((lane & 7) ^ srow) * 8;       // staging: swizzled bf16 col

    // Reader swizzle: logical chunk (ks*4+quad) of row rr lives at physical
    // chunk ((ks*4+quad) ^ (rr&7)); rr&7 == r&7 for all fragment rows.
    int csw0 = ((quad ^ (r & 7)) * 8);        // element offset, ks=0

    // Strength-reduced staging pointers (advance by BK per K-iter).
    const unsigned short* gA = A  + (size_t)(m0 + wave * 8 + srow) * GK + scol;
    const unsigned short* gB = Wq + (size_t)(n0 + wave * 8 + srow) * GK + scol;

    f32x4 acc[4][4] = {};

    for (int k0 = 0; k0 < GK; k0 += BK) {
        // stage A tile (128 rows x 64 cols bf16): 4 issues of 16B per thread
#pragma unroll
        for (int i = 0; i < 4; i++) {
            int row = i * 32 + wave * 8;
            __builtin_amdgcn_global_load_lds(
                (const __attribute__((address_space(1))) void*)(const void*)(gA + (size_t)i * 32 * GK),
                (__attribute__((address_space(3))) void*)(void*)(lsA + row * BK), 16, 0, 0);
        }
        // stage W tile (128 rows x 64 cols bf16)
#pragma unroll
        for (int i = 0; i < 4; i++) {
            int row = i * 32 + wave * 8;
            __builtin_amdgcn_global_load_lds(
                (const __attribute__((address_space(1))) void*)(const void*)(gB + (size_t)i * 32 * GK),
                (__attribute__((address_space(3))) void*)(void*)(lsB + row * BK), 16, 0, 0);
        }
        gA += BK;
        gB += BK;
        __syncthreads();
#pragma unroll
        for (int ks = 0; ks < 2; ks++) {
            bf16x8 af[4], bfr[4];
            const short* pa = (const short*)lsA;
            const short* pb = (const short*)lsB;
            int coff = csw0 ^ (ks * 32);
#pragma unroll
            for (int i = 0; i < 4; i++)
                af[i] = *(const bf16x8*)(pa + (wm + i * 16 + r) * BK + coff);
#pragma unroll
            for (int j2 = 0; j2 < 4; j2++)
                bfr[j2] = *(const bf16x8*)(pb + (wn + j2 * 16 + r) * BK + coff);
#pragma unroll
            for (int i = 0; i < 4; i++)
#pragma unroll
                for (int j2 = 0; j2 < 4; j2++)
                    acc[i][j2] = __builtin_amdgcn_mfma_f32_16x16x32_bf16(
                        af[i], bfr[j2], acc[i][j2], 0, 0, 0);
        }
        __syncthreads();
    }

    // Epilogue: per-block uniform half selection (BN=128 divides D_OUT)
    float s_re = sums[0] * (1.0f / (2048.0f * 2048.0f));
    float s_im = sums[1] * (1.0f / (2048.0f * 2048.0f));
    float scale;
    float* obase;
    int ncol0;
    if (n0 < D_OUT) { scale = s_re; obase = out;                        ncol0 = n0; }
    else            { scale = s_im; obase = out + (size_t)GM * D_OUT;   ncol0 = n0 - D_OUT; }

#pragma unroll
    for (int i = 0; i < 4; i++)
#pragma unroll
        for (int j2 = 0; j2 < 4; j2++) {
            int mrow = m0 + wm + i * 16 + quad * 4;   // C/D layout: row=(lane>>4)*4+reg
            int ncol = ncol0 + wn + j2 * 16 + r;      // col = lane&15
#pragma unroll
            for (int reg = 0; reg < 4; reg++)
                obase[(size_t)(mrow + reg) * D_OUT + ncol] = acc[i][j2][reg] * scale;
        }
}

extern "C" void kernel_launch(void* const* d_in, const int* in_sizes, int n_in,
                              void* d_out, int out_size, void* d_ws, size_t ws_size,
                              hipStream_t stream) {
    const float* xr    = (const float*)d_in[0];
    const float* xi    = (const float*)d_in[1];
    const float* wre   = (const float*)d_in[2];
    const float* wim   = (const float*)d_in[3];
    const float* gamma = (const float*)d_in[4];
    const float* beta  = (const float*)d_in[5];
    float* out = (float*)d_out;

    // ws layout: A bf16 (GM*GK), W_cat bf16 (GN*GK), partials (2*QB f32), sums (2 f32)
    unsigned short* A  = (unsigned short*)d_ws;
    unsigned short* Wq = (unsigned short*)((char*)d_ws + (size_t)GM * GK * 2);
    float* partial = (float*)((char*)d_ws + (size_t)GM * GK * 2 + (size_t)GN * GK * 2);
    float* sums = partial + 2 * QB;

    quant_kernel<<<QB, 256, 0, stream>>>(wre, wim, Wq, partial);
    reduce_kernel<<<1, 256, 0, stream>>>(partial, sums);
    ln_kernel<<<GM, 256, 0, stream>>>(xr, xi, gamma, beta, A);
    gemm_kernel<<<(GN / 128) * (GM / 128), 256, 0, stream>>>(A, Wq, sums, out);
}